// Round 1
// baseline (250.759 us; speedup 1.0000x reference)
//
#include <hip/hip_runtime.h>
#include <stdint.h>

#define B_  32
#define D_  192
#define TX_ 256
#define TY_ 1024
#define NEGV -1e9f
// -0.5*log(2*pi)*D, computed in double, cast to f32 (matches reference const)
#define LPCONST ((float)(-176.43619837529715))

// ---------------- K0: row/col squared-norm terms -------------------------
// xsq[b][t] = -0.5*sum_d x[b][d][t]^2   (32x256)
// ysq[b][s] = -0.5*sum_d y[b][d][s]^2   (32x1024)
__global__ __launch_bounds__(256) void k0_sq(const float* __restrict__ x,
                                             const float* __restrict__ y,
                                             float* __restrict__ xsq,
                                             float* __restrict__ ysq) {
    int gid = blockIdx.x * 256 + threadIdx.x;
    if (gid < B_ * TX_) {
        int b = gid >> 8, t = gid & 255;
        const float* p = x + (size_t)b * D_ * TX_ + t;
        float s = 0.f;
        #pragma unroll 8
        for (int d = 0; d < D_; ++d) { float v = p[(size_t)d * TX_]; s += v * v; }
        xsq[gid] = -0.5f * s;
    } else {
        int g = gid - B_ * TX_;
        int b = g >> 10, t = g & 1023;
        const float* p = y + (size_t)b * D_ * TY_ + t;
        float s = 0.f;
        #pragma unroll 8
        for (int d = 0; d < D_; ++d) { float v = p[(size_t)d * TY_]; s += v * v; }
        ysq[g] = -0.5f * s;
    }
}

// ---------------- K1: log_prior GEMM ------------------------------------
// lp[b][s][t] = xy + xsq[t] + ysq[s] + C   layout: column s contiguous in t
// 128(t) x 128(s) tile, 256 threads, 8x8 per thread, K-chunk 32.
#define BT 128
#define BS 128
#define BK 32
__global__ __launch_bounds__(256) void k1_gemm(const float* __restrict__ x,
                                               const float* __restrict__ y,
                                               const float* __restrict__ xsq,
                                               const float* __restrict__ ysq,
                                               float* __restrict__ lp) {
    __shared__ float xs[BK][BT];
    __shared__ float ys[BK][BS];
    const int b  = blockIdx.z;
    const int t0 = blockIdx.y * BT;
    const int s0 = blockIdx.x * BS;
    const int tid = threadIdx.x;
    const int ti = tid & 15;   // t-group (fast dim -> coalesced stores)
    const int si = tid >> 4;   // s-group

    float acc[8][8];           // [it][js]
    #pragma unroll
    for (int i = 0; i < 8; ++i)
        #pragma unroll
        for (int j = 0; j < 8; ++j) acc[i][j] = 0.f;

    const float* xg = x + (size_t)b * D_ * TX_ + t0;
    const float* yg = y + (size_t)b * D_ * TY_ + s0;

    for (int k0 = 0; k0 < D_; k0 += BK) {
        #pragma unroll
        for (int i = 0; i < 4; ++i) {
            int f = tid + i * 256;           // 0..1023 float4 slots
            int row = f >> 5;                // 0..31
            int col = (f & 31) * 4;          // 0..124
            float4 v = *(const float4*)(xg + (size_t)(k0 + row) * TX_ + col);
            *(float4*)&xs[row][col] = v;
            float4 w = *(const float4*)(yg + (size_t)(k0 + row) * TY_ + col);
            *(float4*)&ys[row][col] = w;
        }
        __syncthreads();
        #pragma unroll
        for (int k = 0; k < BK; ++k) {
            float xr[8], yr[8];
            *(float4*)&xr[0] = *(float4*)&xs[k][ti * 8];
            *(float4*)&xr[4] = *(float4*)&xs[k][ti * 8 + 4];
            *(float4*)&yr[0] = *(float4*)&ys[k][si * 8];
            *(float4*)&yr[4] = *(float4*)&ys[k][si * 8 + 4];
            #pragma unroll
            for (int i = 0; i < 8; ++i)
                #pragma unroll
                for (int j = 0; j < 8; ++j) acc[i][j] += xr[i] * yr[j];
        }
        __syncthreads();
    }

    float xq[8], yq[8];
    *(float4*)&xq[0] = *(const float4*)(xsq + b * TX_ + t0 + ti * 8);
    *(float4*)&xq[4] = *(const float4*)(xsq + b * TX_ + t0 + ti * 8 + 4);
    *(float4*)&yq[0] = *(const float4*)(ysq + b * TY_ + s0 + si * 8);
    *(float4*)&yq[4] = *(const float4*)(ysq + b * TY_ + s0 + si * 8 + 4);

    #pragma unroll
    for (int js = 0; js < 8; ++js) {
        float* op = lp + (size_t)(b * TY_ + s0 + si * 8 + js) * TX_ + t0 + ti * 8;
        float o[8];
        #pragma unroll
        for (int it = 0; it < 8; ++it) {
            // match reference order: ((y_sq + xy) + x_sq) + const
            float v = yq[js] + acc[it][js];
            v = v + xq[it];
            o[it] = v + LPCONST;
        }
        *(float4*)op       = *(float4*)&o[0];
        *(float4*)(op + 4) = *(float4*)&o[4];
    }
}

// ---------------- K2: forward DP + backtrack ----------------------------
// One wave per batch. lane l owns t = 4l..4l+3. Backpointer bits packed
// row-major (RB[t][word]) in LDS; lane-0 chase writes path[b][yi] bytes.
__global__ __launch_bounds__(64) void k2_dp(const float* __restrict__ lp,
                                            const int* __restrict__ xlens,
                                            const int* __restrict__ ylens,
                                            unsigned char* __restrict__ path) {
    __shared__ unsigned int RB[TX_][33];   // padded: flush is 8-way not 64-way
    const int b = blockIdx.x;
    const int l = threadIdx.x;
    const int xlen = xlens[b];
    const int ylen = ylens[b];
    const int send = (ylen + 31) & ~31;    // >=512, multiple of 32
    const float* base = lp + (size_t)b * TY_ * TX_ + l * 4;
    const int tt0 = l * 4;

#define LDCOL(s) (*(const float4*)(base + (size_t)(((s) < TY_) ? (s) : (TY_ - 1)) * TX_))

    float4 f0 = LDCOL(0), f1 = LDCOL(1), f2 = LDCOL(2), f3 = LDCOL(3);
    float4 f4 = LDCOL(4), f5 = LDCOL(5), f6 = LDCOL(6), f7 = LDCOL(7);

    float p0, p1, p2, p3;
    unsigned int rw0 = 0, rw1 = 0, rw2 = 0, rw3 = 0;

    // s = 0: col0 = where(t==0, lp, NEG)
    p0 = (l == 0) ? f0.x : NEGV;
    p1 = NEGV; p2 = NEGV; p3 = NEGV;
    f0 = LDCOL(8);

#define PROC(s, fv, PRE) {                                            \
    float sh = __shfl_up(p3, 1);                                      \
    unsigned int sbit = 1u << ((s) & 31);                             \
    bool e0 = PRE && (tt0     == (s));                                \
    bool e1 = PRE && (tt0 + 1 == (s));                                \
    bool e2 = PRE && (tt0 + 2 == (s));                                \
    bool e3 = PRE && (tt0 + 3 == (s));                                \
    float vc0 = e0 ? NEGV : p0;                                       \
    float vc1 = e1 ? NEGV : p1;                                       \
    float vc2 = e2 ? NEGV : p2;                                       \
    float vc3 = e3 ? NEGV : p3;                                       \
    float vp0 = (l == 0) ? NEGV : sh;                                 \
    if ((l != 0) && (e0 || (sh > p0))) rw0 |= sbit;                   \
    if (e1 || (p0 > p1)) rw1 |= sbit;                                 \
    if (e2 || (p1 > p2)) rw2 |= sbit;                                 \
    if (e3 || (p2 > p3)) rw3 |= sbit;                                 \
    p0 = (fv).x + fmaxf(vc0, vp0);                                    \
    p1 = (fv).y + fmaxf(vc1, p0 == p0 ? vc1 == vc1 ? __shfl(p0,l) : 0.f : 0.f); \
    p1 = p1; /* placeholder removed below */                          \
}
#undef PROC
    // (clean macro, the above was a typo guard — real one:)
#define PROC(s, fv, PRE) {                                            \
    float sh = __shfl_up(p3, 1);                                      \
    unsigned int sbit = 1u << ((s) & 31);                             \
    bool e0 = PRE && (tt0     == (s));                                \
    bool e1 = PRE && (tt0 + 1 == (s));                                \
    bool e2 = PRE && (tt0 + 2 == (s));                                \
    bool e3 = PRE && (tt0 + 3 == (s));                                \
    float vc0 = e0 ? NEGV : p0;                                       \
    float vc1 = e1 ? NEGV : p1;                                       \
    float vc2 = e2 ? NEGV : p2;                                       \
    float vc3 = e3 ? NEGV : p3;                                       \
    float vp0 = (l == 0) ? NEGV : sh;                                 \
    if ((l != 0) && (e0 || (sh > p0))) rw0 |= sbit;                   \
    if (e1 || (p0 > p1)) rw1 |= sbit;                                 \
    if (e2 || (p1 > p2)) rw2 |= sbit;                                 \
    if (e3 || (p2 > p3)) rw3 |= sbit;                                 \
    float c0 = (fv).x + fmaxf(vc0, vp0);                              \
    float c1 = (fv).y + fmaxf(vc1, p0);                               \
    float c2 = (fv).z + fmaxf(vc2, p1);                               \
    float c3 = (fv).w + fmaxf(vc3, p2);                               \
    p0 = c0; p1 = c1; p2 = c2; p3 = c3;                               \
}

#define FLUSH(w) { RB[tt0][w] = rw0; RB[tt0+1][w] = rw1;              \
                   RB[tt0+2][w] = rw2; RB[tt0+3][w] = rw3;            \
                   rw0 = rw1 = rw2 = rw3 = 0; }

    PROC(1, f1, true) f1 = LDCOL(9);
    PROC(2, f2, true) f2 = LDCOL(10);
    PROC(3, f3, true) f3 = LDCOL(11);
    PROC(4, f4, true) f4 = LDCOL(12);
    PROC(5, f5, true) f5 = LDCOL(13);
    PROC(6, f6, true) f6 = LDCOL(14);
    PROC(7, f7, true) f7 = LDCOL(15);

    for (int sb = 8; sb < 256; sb += 8) {
        PROC(sb + 0, f0, true) f0 = LDCOL(sb + 8);
        PROC(sb + 1, f1, true) f1 = LDCOL(sb + 9);
        PROC(sb + 2, f2, true) f2 = LDCOL(sb + 10);
        PROC(sb + 3, f3, true) f3 = LDCOL(sb + 11);
        PROC(sb + 4, f4, true) f4 = LDCOL(sb + 12);
        PROC(sb + 5, f5, true) f5 = LDCOL(sb + 13);
        PROC(sb + 6, f6, true) f6 = LDCOL(sb + 14);
        PROC(sb + 7, f7, true) f7 = LDCOL(sb + 15);
        if ((sb & 31) == 24) FLUSH(sb >> 5)
    }
    for (int sb = 256; sb < send; sb += 8) {
        PROC(sb + 0, f0, false) f0 = LDCOL(sb + 8);
        PROC(sb + 1, f1, false) f1 = LDCOL(sb + 9);
        PROC(sb + 2, f2, false) f2 = LDCOL(sb + 10);
        PROC(sb + 3, f3, false) f3 = LDCOL(sb + 11);
        PROC(sb + 4, f4, false) f4 = LDCOL(sb + 12);
        PROC(sb + 5, f5, false) f5 = LDCOL(sb + 13);
        PROC(sb + 6, f6, false) f6 = LDCOL(sb + 14);
        PROC(sb + 7, f7, false) f7 = LDCOL(sb + 15);
        if ((sb & 31) == 24) FLUSH(sb >> 5)
    }
    __syncthreads();

    if (l == 0) {
        int idx = xlen - 1;
        unsigned char* pb = path + b * TY_;
        int yi = ylen - 1;
        unsigned int cur = RB[idx][yi >> 5];
        unsigned int n1 = (idx > 0) ? RB[idx - 1][yi >> 5] : 0u;
        while (yi >= 0) {
            pb[yi] = (unsigned char)idx;
            unsigned int mv = (cur >> (yi & 31)) & 1u;
            if (mv) {
                --idx;
                cur = n1;
                n1 = (idx > 0) ? RB[idx - 1][yi >> 5] : 0u;
            }
            if ((yi & 31) == 0 && yi > 0) {
                int w = (yi - 1) >> 5;
                cur = RB[idx][w];
                n1 = (idx > 0) ? RB[idx - 1][w] : 0u;
            }
            --yi;
        }
    }
}

// ---------------- K3: materialize one-hot output ------------------------
__global__ __launch_bounds__(256) void k3_out(const unsigned char* __restrict__ path,
                                              const int* __restrict__ ylens,
                                              float* __restrict__ out) {
    int F = blockIdx.x * 256 + threadIdx.x;       // float4 index, 2M total
    int yi = (F & 255) * 4;
    int t  = (F >> 8) & 255;
    int b  = F >> 16;
    int ylen = ylens[b];
    unsigned int pw = *(const unsigned int*)(path + b * TY_ + yi);
    float4 v;
    v.x = (((pw      ) & 255u) == (unsigned)t && yi     < ylen) ? 1.f : 0.f;
    v.y = (((pw >>  8) & 255u) == (unsigned)t && yi + 1 < ylen) ? 1.f : 0.f;
    v.z = (((pw >> 16) & 255u) == (unsigned)t && yi + 2 < ylen) ? 1.f : 0.f;
    v.w = (((pw >> 24) & 255u) == (unsigned)t && yi + 3 < ylen) ? 1.f : 0.f;
    ((float4*)out)[F] = v;
}

extern "C" void kernel_launch(void* const* d_in, const int* in_sizes, int n_in,
                              void* d_out, int out_size, void* d_ws, size_t ws_size,
                              hipStream_t stream) {
    const float* x  = (const float*)d_in[0];
    const int*   xl = (const int*)d_in[1];
    const float* y  = (const float*)d_in[2];
    const int*   yl = (const int*)d_in[3];
    float* out = (float*)d_out;

    char* ws = (char*)d_ws;
    float* xsq = (float*)ws;                           //  32 KB
    float* ysq = (float*)(ws + 32 * 1024);             // 128 KB
    unsigned char* path = (unsigned char*)(ws + 160 * 1024); // 32 KB

    // reuse d_out (exactly B*TY*TX floats = 32 MB) as log_prior scratch;
    // K3 fully overwrites it afterwards.
    float* lp = out;

    k0_sq  <<<160, 256, 0, stream>>>(x, y, xsq, ysq);
    k1_gemm<<<dim3(TY_ / BS, TX_ / BT, B_), 256, 0, stream>>>(x, y, xsq, ysq, lp);
    k2_dp  <<<B_, 64, 0, stream>>>(lp, xl, yl, path);
    k3_out <<<(B_ * TX_ * TY_ / 4) / 256, 256, 0, stream>>>(path, yl, out);
}

// Round 2
// 185.523 us; speedup vs baseline: 1.3516x; 1.3516x over previous
//
#include <hip/hip_runtime.h>
#include <stdint.h>

#define B_  32
#define D_  192
#define TX_ 256
#define TY_ 1024
#define NEGV -1e9f
// -0.5*log(2*pi)*D, computed in double, cast to f32 (matches reference const)
#define LPCONST ((float)(-176.43619837529715))

// ---------------- K0: row/col squared-norm terms -------------------------
__global__ __launch_bounds__(256) void k0_sq(const float* __restrict__ x,
                                             const float* __restrict__ y,
                                             float* __restrict__ xsq,
                                             float* __restrict__ ysq) {
    int gid = blockIdx.x * 256 + threadIdx.x;
    if (gid < B_ * TX_) {
        int b = gid >> 8, t = gid & 255;
        const float* p = x + (size_t)b * D_ * TX_ + t;
        float s = 0.f;
        #pragma unroll 8
        for (int d = 0; d < D_; ++d) { float v = p[(size_t)d * TX_]; s += v * v; }
        xsq[gid] = -0.5f * s;
    } else {
        int g = gid - B_ * TX_;
        int b = g >> 10, t = g & 1023;
        const float* p = y + (size_t)b * D_ * TY_ + t;
        float s = 0.f;
        #pragma unroll 8
        for (int d = 0; d < D_; ++d) { float v = p[(size_t)d * TY_]; s += v * v; }
        ysq[g] = -0.5f * s;
    }
}

// ---------------- K1: log_prior GEMM ------------------------------------
// lp[b][s][t] = xy + xsq[t] + ysq[s] + C
// 1D grid, remapped so all 16 tiles of batch b have linear id == b (mod 8):
// under id%8 -> XCD round-robin, batch b's lp lives in XCD (b%8)'s L2,
// which is where k2's block b (grid id = b) runs. Perf heuristic only.
#define BT 128
#define BS 128
#define BK 32
__global__ __launch_bounds__(256) void k1_gemm(const float* __restrict__ x,
                                               const float* __restrict__ y,
                                               const float* __restrict__ xsq,
                                               const float* __restrict__ ysq,
                                               float* __restrict__ lp) {
    __shared__ float xs[BK][BT];
    __shared__ float ys[BK][BS];
    const int id = blockIdx.x;            // 0..511
    const int r  = id & 7;
    const int g  = id >> 3;               // 0..63
    const int b  = r + 8 * (g >> 4);      // 0..31
    const int sub = g & 15;               // 16 tiles per batch
    const int t0 = (sub >> 3) * BT;       // 2 t-tiles
    const int s0 = (sub & 7) * BS;        // 8 s-tiles
    const int tid = threadIdx.x;
    const int ti = tid & 15;   // t-group (fast dim -> coalesced stores)
    const int si = tid >> 4;   // s-group

    float acc[8][8];
    #pragma unroll
    for (int i = 0; i < 8; ++i)
        #pragma unroll
        for (int j = 0; j < 8; ++j) acc[i][j] = 0.f;

    const float* xg = x + (size_t)b * D_ * TX_ + t0;
    const float* yg = y + (size_t)b * D_ * TY_ + s0;

    for (int k0 = 0; k0 < D_; k0 += BK) {
        #pragma unroll
        for (int i = 0; i < 4; ++i) {
            int f = tid + i * 256;           // 0..1023 float4 slots
            int row = f >> 5;                // 0..31
            int col = (f & 31) * 4;          // 0..124
            float4 v = *(const float4*)(xg + (size_t)(k0 + row) * TX_ + col);
            *(float4*)&xs[row][col] = v;
            float4 w = *(const float4*)(yg + (size_t)(k0 + row) * TY_ + col);
            *(float4*)&ys[row][col] = w;
        }
        __syncthreads();
        #pragma unroll
        for (int k = 0; k < BK; ++k) {
            float xr[8], yr[8];
            *(float4*)&xr[0] = *(float4*)&xs[k][ti * 8];
            *(float4*)&xr[4] = *(float4*)&xs[k][ti * 8 + 4];
            *(float4*)&yr[0] = *(float4*)&ys[k][si * 8];
            *(float4*)&yr[4] = *(float4*)&ys[k][si * 8 + 4];
            #pragma unroll
            for (int i = 0; i < 8; ++i)
                #pragma unroll
                for (int j = 0; j < 8; ++j) acc[i][j] += xr[i] * yr[j];
        }
        __syncthreads();
    }

    float xq[8], yq[8];
    *(float4*)&xq[0] = *(const float4*)(xsq + b * TX_ + t0 + ti * 8);
    *(float4*)&xq[4] = *(const float4*)(xsq + b * TX_ + t0 + ti * 8 + 4);
    *(float4*)&yq[0] = *(const float4*)(ysq + b * TY_ + s0 + si * 8);
    *(float4*)&yq[4] = *(const float4*)(ysq + b * TY_ + s0 + si * 8 + 4);

    #pragma unroll
    for (int js = 0; js < 8; ++js) {
        float* op = lp + (size_t)(b * TY_ + s0 + si * 8 + js) * TX_ + t0 + ti * 8;
        float o[8];
        #pragma unroll
        for (int it = 0; it < 8; ++it) {
            // match reference order: ((y_sq + xy) + x_sq) + const
            float v = yq[js] + acc[it][js];
            v = v + xq[it];
            o[it] = v + LPCONST;
        }
        *(float4*)op       = *(float4*)&o[0];
        *(float4*)(op + 4) = *(float4*)&o[4];
    }
}

// ---------------- K2: forward DP + backtrack ----------------------------
// One wave per batch. Lane l owns t = 4l..4l+3.
// 16-column float4 prefetch ring; shuffle issued off the critical chain
// (shfl of this column's c3 is consumed by NEXT column's c0).
// Backpointer bits packed row-major RB[t][word] in LDS; run-length
// backtrack via __clz, path staged in LDS, wave-parallel copy out.
__global__ __launch_bounds__(64) void k2_dp(const float* __restrict__ lp,
                                            const int* __restrict__ xlens,
                                            const int* __restrict__ ylens,
                                            unsigned char* __restrict__ path) {
    __shared__ unsigned int RB[TX_][33];   // padded stride
    __shared__ unsigned int PTw[TY_ / 4];  // path bytes staged as words
    unsigned char* PT = (unsigned char*)PTw;

    const int b = blockIdx.x;
    const int l = threadIdx.x;
    const int xlen = xlens[b];
    const int ylen = ylens[b];
    const int send = (ylen + 31) & ~31;    // >=512, multiple of 32
    const float* base = lp + (size_t)b * TY_ * TX_ + l * 4;
    const int tt0 = l * 4;

#define LDCOL(s) (*(const float4*)(base + (size_t)(((s) < TY_) ? (s) : (TY_ - 1)) * TX_))

// entry: p0..p3 = column (s-1) values; shv = shfl_up of p3 at column (s-1).
// bits at column s compare column (s-1) values (reference backtrack predicate).
#define PROC(s, fv, PRE) {                                              \
    unsigned int sbit = 1u << ((s) & 31);                               \
    bool e0 = false, e1 = false, e2 = false, e3 = false;                \
    if (PRE) { e0 = (tt0 == (s));     e1 = (tt0 + 1 == (s));            \
               e2 = (tt0 + 2 == (s)); e3 = (tt0 + 3 == (s)); }          \
    if ((l != 0) && (e0 || (shv > p0))) rw0 |= sbit;                    \
    if (e1 || (p0 > p1)) rw1 |= sbit;                                   \
    if (e2 || (p1 > p2)) rw2 |= sbit;                                   \
    if (e3 || (p2 > p3)) rw3 |= sbit;                                   \
    float c3 = (fv).w + fmaxf(e3 ? NEGV : p3, p2);                      \
    float nsh = __shfl_up(c3, 1);                                       \
    float c2 = (fv).z + fmaxf(e2 ? NEGV : p2, p1);                      \
    float c1 = (fv).y + fmaxf(e1 ? NEGV : p1, p0);                      \
    float c0 = (fv).x + fmaxf(e0 ? NEGV : p0, (l == 0) ? NEGV : shv);   \
    p0 = c0; p1 = c1; p2 = c2; p3 = c3; shv = nsh;                      \
}

#define FLUSH(w) { RB[tt0][w] = rw0; RB[tt0 + 1][w] = rw1;              \
                   RB[tt0 + 2][w] = rw2; RB[tt0 + 3][w] = rw3;          \
                   rw0 = rw1 = rw2 = rw3 = 0; }

    float4 g[16];
    #pragma unroll
    for (int i = 0; i < 16; ++i) g[i] = LDCOL(i);

    float p0, p1, p2, p3, shv;
    unsigned int rw0 = 0, rw1 = 0, rw2 = 0, rw3 = 0;

    // s = 0: col0 = where(t==0, lp, NEG)
    p0 = (l == 0) ? g[0].x : NEGV;
    p1 = NEGV; p2 = NEGV; p3 = NEGV;
    shv = NEGV;                      // shfl of p3@col0 (all NEGV)
    g[0] = LDCOL(16);

    #pragma unroll
    for (int j = 1; j < 16; ++j) { PROC(j, g[j], true) g[j] = LDCOL(16 + j); }

    #pragma unroll 1
    for (int sb = 16; sb < 256; sb += 16) {
        #pragma unroll
        for (int j = 0; j < 16; ++j) { PROC(sb + j, g[j], true) g[j] = LDCOL(sb + 16 + j); }
        if (((sb + 15) & 31) == 31) FLUSH((sb + 15) >> 5)
    }
    #pragma unroll 1
    for (int sb = 256; sb < send; sb += 16) {
        #pragma unroll
        for (int j = 0; j < 16; ++j) { PROC(sb + j, g[j], false) g[j] = LDCOL(sb + 16 + j); }
        if (((sb + 15) & 31) == 31) FLUSH((sb + 15) >> 5)
    }
    __syncthreads();

    if (l == 0) {
        // run-length backtrack: highest set bit <= yi in row idx's word
        // gives the column where the next down-move happens.
        int idx = xlen - 1;
        int yi = ylen - 1;
        while (yi >= 0) {
            int w = yi >> 5;
            unsigned int cur = RB[idx][w] & (0xFFFFFFFFu >> (31 - (yi & 31)));
            int lo; bool mv;
            if (cur) { lo = (w << 5) + (31 - __clz(cur)); mv = true; }
            else     { lo = (w << 5);                      mv = false; }
            for (int q = lo; q <= yi; ++q) PT[q] = (unsigned char)idx;
            if (mv) --idx;
            yi = lo - 1;
        }
    }
    __syncthreads();
    {
        unsigned int* pd = (unsigned int*)(path + b * TY_);
        #pragma unroll
        for (int k = 0; k < 4; ++k) pd[l + k * 64] = PTw[l + k * 64];
    }
}

// ---------------- K3: materialize one-hot output ------------------------
__global__ __launch_bounds__(256) void k3_out(const unsigned char* __restrict__ path,
                                              const int* __restrict__ ylens,
                                              float* __restrict__ out) {
    int F = blockIdx.x * 256 + threadIdx.x;       // float4 index, 2M total
    int yi = (F & 255) * 4;
    int t  = (F >> 8) & 255;
    int b  = F >> 16;
    int ylen = ylens[b];
    unsigned int pw = *(const unsigned int*)(path + b * TY_ + yi);
    float4 v;
    v.x = (((pw      ) & 255u) == (unsigned)t && yi     < ylen) ? 1.f : 0.f;
    v.y = (((pw >>  8) & 255u) == (unsigned)t && yi + 1 < ylen) ? 1.f : 0.f;
    v.z = (((pw >> 16) & 255u) == (unsigned)t && yi + 2 < ylen) ? 1.f : 0.f;
    v.w = (((pw >> 24) & 255u) == (unsigned)t && yi + 3 < ylen) ? 1.f : 0.f;
    ((float4*)out)[F] = v;
}

extern "C" void kernel_launch(void* const* d_in, const int* in_sizes, int n_in,
                              void* d_out, int out_size, void* d_ws, size_t ws_size,
                              hipStream_t stream) {
    const float* x  = (const float*)d_in[0];
    const int*   xl = (const int*)d_in[1];
    const float* y  = (const float*)d_in[2];
    const int*   yl = (const int*)d_in[3];
    float* out = (float*)d_out;

    char* ws = (char*)d_ws;
    float* xsq = (float*)ws;                           //  32 KB
    float* ysq = (float*)(ws + 32 * 1024);             // 128 KB
    unsigned char* path = (unsigned char*)(ws + 160 * 1024); // 32 KB

    // reuse d_out (exactly B*TY*TX floats = 32 MB) as log_prior scratch;
    // K3 fully overwrites it afterwards.
    float* lp = out;

    k0_sq  <<<160, 256, 0, stream>>>(x, y, xsq, ysq);
    k1_gemm<<<512, 256, 0, stream>>>(x, y, xsq, ysq, lp);
    k2_dp  <<<B_, 64, 0, stream>>>(lp, xl, yl, path);
    k3_out <<<(B_ * TX_ * TY_ / 4) / 256, 256, 0, stream>>>(path, yl, out);
}